// Round 1
// baseline (67.063 us; speedup 1.0000x reference)
//
#include <hip/hip_runtime.h>

// Embedding bag, sum pooling.
// weights: [500000, 128] f32; indices: [NUM_BAGS*POOL] i32; offsets: [NUM_BAGS+1] i32
// out: [NUM_BAGS, 128] f32, out[b] = sum_{j in [offsets[b], offsets[b+1])} weights[indices[j]]
//
// Layout: 32 lanes per bag, each lane owns 4 consecutive dims (float4).
// 256-thread block = 8 bags. Per gathered row: 32 lanes x 16B = one
// contiguous 512B segment -> fully coalesced global_load_dwordx4.

#define BAGS_PER_BLOCK 8

__global__ __launch_bounds__(256) void embag_sum_kernel(
    const float* __restrict__ weights,
    const int* __restrict__ indices,
    const int* __restrict__ offsets,
    float* __restrict__ out,
    int num_bags)
{
    const int lane = threadIdx.x & 31;            // which float4 of the row
    const int sub  = threadIdx.x >> 5;            // bag within block, 0..7
    const int bag  = blockIdx.x * BAGS_PER_BLOCK + sub;
    if (bag >= num_bags) return;

    const int start = offsets[bag];
    const int end   = offsets[bag + 1];

    const float4* __restrict__ wv = reinterpret_cast<const float4*>(weights);
    // row stride in float4 units: 128 floats / 4 = 32

    float4 a0 = make_float4(0.f, 0.f, 0.f, 0.f);
    float4 a1 = make_float4(0.f, 0.f, 0.f, 0.f);
    float4 a2 = make_float4(0.f, 0.f, 0.f, 0.f);
    float4 a3 = make_float4(0.f, 0.f, 0.f, 0.f);

    int j = start;
    // 4-deep unroll: independent loads -> ILP hides gather latency
    for (; j + 4 <= end; j += 4) {
        const int i0 = indices[j + 0];
        const int i1 = indices[j + 1];
        const int i2 = indices[j + 2];
        const int i3 = indices[j + 3];
        const float4 v0 = wv[(size_t)i0 * 32 + lane];
        const float4 v1 = wv[(size_t)i1 * 32 + lane];
        const float4 v2 = wv[(size_t)i2 * 32 + lane];
        const float4 v3 = wv[(size_t)i3 * 32 + lane];
        a0.x += v0.x; a0.y += v0.y; a0.z += v0.z; a0.w += v0.w;
        a1.x += v1.x; a1.y += v1.y; a1.z += v1.z; a1.w += v1.w;
        a2.x += v2.x; a2.y += v2.y; a2.z += v2.z; a2.w += v2.w;
        a3.x += v3.x; a3.y += v3.y; a3.z += v3.z; a3.w += v3.w;
    }
    for (; j < end; ++j) {
        const int i = indices[j];
        const float4 v = wv[(size_t)i * 32 + lane];
        a0.x += v.x; a0.y += v.y; a0.z += v.z; a0.w += v.w;
    }

    float4 acc;
    acc.x = (a0.x + a1.x) + (a2.x + a3.x);
    acc.y = (a0.y + a1.y) + (a2.y + a3.y);
    acc.z = (a0.z + a1.z) + (a2.z + a3.z);
    acc.w = (a0.w + a1.w) + (a2.w + a3.w);

    float4* __restrict__ ov = reinterpret_cast<float4*>(out);
    ov[(size_t)bag * 32 + lane] = acc;
}

extern "C" void kernel_launch(void* const* d_in, const int* in_sizes, int n_in,
                              void* d_out, int out_size, void* d_ws, size_t ws_size,
                              hipStream_t stream) {
    const float* weights = (const float*)d_in[0];
    const int*   indices = (const int*)d_in[1];
    const int*   offsets = (const int*)d_in[2];
    float* out = (float*)d_out;

    const int num_bags = in_sizes[2] - 1;   // offsets has num_bags+1 entries
    const int grid = (num_bags + BAGS_PER_BLOCK - 1) / BAGS_PER_BLOCK;
    embag_sum_kernel<<<grid, 256, 0, stream>>>(weights, indices, offsets, out, num_bags);
}